// Round 11
// baseline (80.037 us; speedup 1.0000x reference)
//
#include <hip/hip_runtime.h>
#include <math.h>
#include <stdint.h>

// Chamfer loss, B=16, N=M=4096, D=3, fp32 in/out — MFMA formulation, R11.
//
// d^2(p,t) = |p|^2 + (|t|^2 - 2 p.t); the bracket via v_mfma_f32_32x32x16_f16:
//   A row (candidate): [tx, ty, tz, h1, h2, 0,0,0]   (k=0..7; hi-lane k=8..15 garbage)
//   B col (query):     [-2px,-2py,-2pz, 1, 1, 0,0,0] (k=0..7; k=8..15 ZERO -> annihilates A garbage)
// h1+h2 = two-f16 split of |t|^2 (fp32-accurate). f16 products are exact in the
// fp32 accumulator; only error is f16 point quantization (~1e-3 absmax, passes).
//
// R11 delta vs R10 (77.0, neutral — compiler already min3-fuses R9's chains):
// main is ~2x above its MFMA-pipe floor (16.4k cyc/CU) due to the structural
// MFMA-result->VALU read hazard (we must min-reduce every MFMA result; no AGPR
// parking like GEMM). Occupancy/prefetch/chain levers are exhausted. Remaining
// controllable cost: node count. PREP IS FUSED INTO MAIN with no grid sync:
// each block packs the 2048-candidate slab it needs into LDS (32 KB, 2 passes
// over its 4096 candidates; 4 blocks/CU x 32KB <= 160KB) and packs its 2 query
// fragments in registers. 32x redundant pack VALU (~1us) buys: -1 graph node,
// -1 full-grid drain boundary, no packP/packT ws round-trip. ds_read_b128
// broadcast after block-local __syncthreads = standard m33 pattern (R4's
// failure was async global_load_lds, not LDS reads).
//
// Fixed cost context: harness re-poisons ~256 MB ws each timed iter = ~41.3 us
// of fillBuffer at HBM roofline inside dur_us. Untouchable floor.

#define BATCH   16
#define NPTS    4096
#define THREADS 256                            // 4 waves/block
#define NITEMS  (2 * BATCH * NPTS)             // 131072
#define MAIN_BLOCKS (2 * BATCH * (NPTS / 128)) // 1024: 128 queries per block
#define SLAB    2048                           // candidates packed per LDS pass

typedef __attribute__((ext_vector_type(8)))  _Float16 half8;
typedef __attribute__((ext_vector_type(16))) float    floatx16;

union Pack16 { float4 f4; _Float16 h[8]; half8 h8; };

__device__ inline Pack16 pack_point(float x, float y, float z) {
    _Float16 hx = (_Float16)x, hy = (_Float16)y, hz = (_Float16)z;
    float xf = (float)hx, yf = (float)hy, zf = (float)hz;
    float t = xf * xf + yf * yf + zf * zf;        // |q|^2 of the QUANTIZED point
    _Float16 h1 = (_Float16)t;
    _Float16 h2 = (_Float16)(t - (float)h1);
    Pack16 p;
    p.h[0] = hx; p.h[1] = hy; p.h[2] = hz; p.h[3] = h1; p.h[4] = h2;
    p.h[5] = (_Float16)0.0f; p.h[6] = (_Float16)0.0f; p.h[7] = (_Float16)0.0f;
    return p;
}

__device__ inline half8 make_bfrag(const Pack16& praw, bool lo) {
    half8 f;
#pragma unroll
    for (int i = 0; i < 8; ++i) f[i] = (_Float16)0.0f;
    if (lo) {
        f[0] = (_Float16)(praw.h[0] * (_Float16)-2.0f);  // exact x2 scale
        f[1] = (_Float16)(praw.h[1] * (_Float16)-2.0f);
        f[2] = (_Float16)(praw.h[2] * (_Float16)-2.0f);
        f[3] = (_Float16)1.0f;
        f[4] = (_Float16)1.0f;
    }
    return f;
}

__global__ __launch_bounds__(THREADS, 4) void chamfer_main(
    const float* __restrict__ pred, const float* __restrict__ target,
    float* __restrict__ blocksum)
{
    __shared__ __align__(16) float4 cbuf[SLAB];   // 32 KB candidate slab
    __shared__ float pmin[4][64];                 // per-wave mins for its 64 queries
    __shared__ float wsum[2];

    int tid  = threadIdx.x;
    int lane = tid & 63;
    int wave = tid >> 6;            // 0..3
    int qhalf = wave & 1;           // query half (64 of the block's 128 queries)
    int chalf = wave >> 1;          // candidate half within a slab (1024)
    int l31  = lane & 31;
    bool lo  = lane < 32;

    int id = blockIdx.x;
    int ng = id & 31; id >>= 5;     // query group (128 queries)
    int b  = id & 15; id >>= 4;
    int dir = id;                   // 0: queries=pred, candidates=target

    const float* qsrc = (dir ? target : pred) + (size_t)b * (NPTS * 3);
    const float* csrc = (dir ? pred : target) + (size_t)b * (NPTS * 3);

    // Pack this wave's two query fragments in registers (quantization
    // identical to pack_point so psq in the epilogue is consistent).
    int q0 = ng * 128 + qhalf * 64 + l31;
    Pack16 prA = pack_point(qsrc[q0 * 3], qsrc[q0 * 3 + 1], qsrc[q0 * 3 + 2]);
    Pack16 prB = pack_point(qsrc[(q0 + 32) * 3], qsrc[(q0 + 32) * 3 + 1], qsrc[(q0 + 32) * 3 + 2]);
    half8 bfragA = make_bfrag(prA, lo);
    half8 bfragB = make_bfrag(prB, lo);

    floatx16 zero, mnA, mnB;
#pragma unroll
    for (int r = 0; r < 16; ++r) { zero[r] = 0.0f; mnA[r] = 1e30f; mnB[r] = 1e30f; }

    // Two passes: pack 2048 candidates into LDS, then each wave sweeps its
    // 1024-candidate half (16 a0/a1 tile-pairs) with two independent
    // MFMA->min chains (R9 structure — the proven ILP winner).
    for (int pass = 0; pass < 2; ++pass) {
        __syncthreads();                          // previous pass fully read
#pragma unroll
        for (int i = tid; i < SLAB; i += THREADS) {
            int c = pass * SLAB + i;
            cbuf[i] = pack_point(csrc[c * 3], csrc[c * 3 + 1], csrc[c * 3 + 2]).f4;
        }
        __syncthreads();

        const float4* cb = &cbuf[chalf * 1024];
#pragma unroll 2
        for (int t = 0; t < 16; ++t) {
            Pack16 a0, a1;
            a0.f4 = cb[t * 64 + l31];             // half-wave broadcast ds_read_b128
            a1.f4 = cb[t * 64 + 32 + l31];
            floatx16 d0 = __builtin_amdgcn_mfma_f32_32x32x16_f16(a0.h8, bfragA, zero, 0, 0, 0);
            floatx16 d1 = __builtin_amdgcn_mfma_f32_32x32x16_f16(a0.h8, bfragB, zero, 0, 0, 0);
#pragma unroll
            for (int r = 0; r < 16; ++r) mnA[r] = fminf(d0[r], mnA[r]);
#pragma unroll
            for (int r = 0; r < 16; ++r) mnB[r] = fminf(d1[r], mnB[r]);
            floatx16 d2 = __builtin_amdgcn_mfma_f32_32x32x16_f16(a1.h8, bfragA, zero, 0, 0, 0);
            floatx16 d3 = __builtin_amdgcn_mfma_f32_32x32x16_f16(a1.h8, bfragB, zero, 0, 0, 0);
#pragma unroll
            for (int r = 0; r < 16; ++r) mnA[r] = fminf(d2[r], mnA[r]);
#pragma unroll
            for (int r = 0; r < 16; ++r) mnB[r] = fminf(d3[r], mnB[r]);
        }
    }

    // Per-lane 16-reg min trees, fold row-halves across lane^32, publish both
    // query sets (cols l31 / l31+32 of pmin row).
    float mA = fminf(fminf(fminf(mnA[0], mnA[1]),   fminf(mnA[2], mnA[3])),
                     fminf(fminf(mnA[4], mnA[5]),   fminf(mnA[6], mnA[7])));
    mA = fminf(mA, fminf(fminf(fminf(mnA[8], mnA[9]),   fminf(mnA[10], mnA[11])),
                         fminf(fminf(mnA[12], mnA[13]), fminf(mnA[14], mnA[15]))));
    float mB = fminf(fminf(fminf(mnB[0], mnB[1]),   fminf(mnB[2], mnB[3])),
                     fminf(fminf(mnB[4], mnB[5]),   fminf(mnB[6], mnB[7])));
    mB = fminf(mB, fminf(fminf(fminf(mnB[8], mnB[9]),   fminf(mnB[10], mnB[11])),
                         fminf(fminf(mnB[12], mnB[13]), fminf(mnB[14], mnB[15]))));
    mA = fminf(mA, __shfl_xor(mA, 32));
    mB = fminf(mB, __shfl_xor(mB, 32));
    if (lo) {
        pmin[wave][l31]      = mA;
        pmin[wave][l31 + 32] = mB;
    }
    __syncthreads();

    // Waves 0-1: all 64 lanes finish one query each (query = ng*128 + wave*64
    // + lane): merge candidate halves, add |p|^2 (recomputed with the SAME
    // quantization as bfrag), sqrt, full-wave sum.
    if (wave < 2) {
        float mm = fminf(pmin[wave][lane], pmin[wave + 2][lane]);
        int q = ng * 128 + wave * 64 + lane;
        Pack16 pr = pack_point(qsrc[q * 3], qsrc[q * 3 + 1], qsrc[q * 3 + 2]);
        float psq = (float)pr.h[3] + (float)pr.h[4];
        float dist = sqrtf(fmaxf(mm + psq, 0.0f));
#pragma unroll
        for (int off = 1; off <= 32; off <<= 1)
            dist += __shfl_xor(dist, off);
        if (lane == 0) wsum[wave] = dist;
    }
    __syncthreads();

    if (tid == 0)
        blocksum[blockIdx.x] = wsum[0] + wsum[1];
}

__global__ __launch_bounds__(256) void chamfer_finish(
    const float4* __restrict__ bs, float* __restrict__ out)
{
    __shared__ float ws[4];
    int tid = threadIdx.x;
    float4 v = bs[tid];                   // 1024 block sums = 256 thr x float4
    float s = (v.x + v.y) + (v.z + v.w);
#pragma unroll
    for (int off = 1; off <= 32; off <<= 1)
        s += __shfl_xor(s, off);
    int lane = tid & 63, wave = tid >> 6;
    if (lane == 0) ws[wave] = s;
    __syncthreads();
    if (tid == 0) out[0] = (ws[0] + ws[1] + ws[2] + ws[3]) * (1.0f / (float)NITEMS);
}

extern "C" void kernel_launch(void* const* d_in, const int* in_sizes, int n_in,
                              void* d_out, int out_size, void* d_ws, size_t ws_size,
                              hipStream_t stream) {
    const float* pred   = (const float*)d_in[0];
    const float* target = (const float*)d_in[1];
    float* out = (float*)d_out;

    float* blocksum = (float*)d_ws;       // 1024 floats

    chamfer_main<<<MAIN_BLOCKS, THREADS, 0, stream>>>(pred, target, blocksum);
    chamfer_finish<<<1, 256, 0, stream>>>((const float4*)blocksum, out);
}

// Round 12
// 76.104 us; speedup vs baseline: 1.0517x; 1.0517x over previous
//
#include <hip/hip_runtime.h>
#include <math.h>
#include <stdint.h>

// Chamfer loss, B=16, N=M=4096, D=3, fp32 in/out — MFMA formulation, R12.
// == REVERT to R9, the measured optimum (75.9 us) ==
//
// d^2(p,t) = |p|^2 + (|t|^2 - 2 p.t); the bracket via v_mfma_f32_32x32x16_f16:
//   A row (candidate): [tx, ty, tz, h1, h2, 0,0,0]   (k=0..7; hi-lane k=8..15 garbage)
//   B col (query):     [-2px,-2py,-2pz, 1, 1, 0,0,0] (k=0..7; k=8..15 ZERO -> annihilates A garbage)
// h1+h2 = two-f16 split of |t|^2 (fp32-accurate). f16 products are exact in the
// fp32 accumulator; only error is f16 point quantization (~1e-3 absmax, passes).
//
// Session ledger (what moved, what didn't):
//   R2  scalar VALU formulation ......... 110.7 (main 51, VALU-issue bound)
//   R3  MFMA recast ..................... 86.5
//   R4-R6 fused atomic epilogue ......... 95-103 (REGRESSION: __threadfence
//         emits L2 writeback + 1024 contended device atomics across XCDs)
//   R7  3-node, no atomics .............. 80.7
//   R8  full-occupancy regrid+prefetch .. 80.9 (neutral -> not occupancy/loads)
//   R9  TWO independent MFMA->min chains  75.9 (WIN: dep-chain ILP is binding)
//   R10 min3 pairing .................... 77.0 (neutral: compiler already fuses)
//   R11 prep fused via LDS pack ......... 80.0 (REGRESSION: 32x redundant pack)
// Floor analysis: dur = ~41.4us harness ws re-poison (256 MiB fill at 81% HBM
// peak, untouchable) + ~22us main + ~4us prep/finish + ~8us launch overhead.
// Main is within ~2x of its MFMA-pipe roofline (16.5k cyc/SIMD); the residual
// is the structural MFMA-result->VALU read hazard (every MFMA result must be
// min-reduced in VALU — no AGPR parking as in GEMM). All identified levers
// (occupancy, load path, prefetch, chain ILP, min density, node fusion) are
// measured; only chain ILP helped.

#define BATCH   16
#define NPTS    4096
#define THREADS 256                            // 4 waves/block
#define NITEMS  (2 * BATCH * NPTS)             // 131072
#define MAIN_BLOCKS (2 * BATCH * (NPTS / 128)) // 1024: 128 queries per block

typedef __attribute__((ext_vector_type(8)))  _Float16 half8;
typedef __attribute__((ext_vector_type(16))) float    floatx16;

union Pack16 { float4 f4; _Float16 h[8]; half8 h8; };

__global__ __launch_bounds__(256) void chamfer_prep(
    const float* __restrict__ pred, const float* __restrict__ target,
    float4* __restrict__ packP, float4* __restrict__ packT)
{
    int g = blockIdx.x * 256 + threadIdx.x;       // 0..131071
    int arr = g >> 16;                            // 0=pred, 1=target
    int pt  = g & 65535;                          // b*NPTS + n
    const float* src = arr ? target : pred;
    float x = src[pt * 3 + 0];
    float y = src[pt * 3 + 1];
    float z = src[pt * 3 + 2];
    _Float16 hx = (_Float16)x, hy = (_Float16)y, hz = (_Float16)z;
    float xf = (float)hx, yf = (float)hy, zf = (float)hz;
    float t = xf * xf + yf * yf + zf * zf;        // |q|^2 of the QUANTIZED point
    _Float16 h1 = (_Float16)t;
    _Float16 h2 = (_Float16)(t - (float)h1);
    Pack16 p;
    p.h[0] = hx; p.h[1] = hy; p.h[2] = hz; p.h[3] = h1; p.h[4] = h2;
    p.h[5] = (_Float16)0.0f; p.h[6] = (_Float16)0.0f; p.h[7] = (_Float16)0.0f;
    (arr ? packT : packP)[pt] = p.f4;
}

__device__ inline half8 make_bfrag(const Pack16& praw, bool lo) {
    half8 f;
#pragma unroll
    for (int i = 0; i < 8; ++i) f[i] = (_Float16)0.0f;
    if (lo) {
        f[0] = (_Float16)(praw.h[0] * (_Float16)-2.0f);  // exact x2 scale
        f[1] = (_Float16)(praw.h[1] * (_Float16)-2.0f);
        f[2] = (_Float16)(praw.h[2] * (_Float16)-2.0f);
        f[3] = (_Float16)1.0f;
        f[4] = (_Float16)1.0f;
    }
    return f;
}

__global__ __launch_bounds__(THREADS, 4) void chamfer_main(
    const float4* __restrict__ packP, const float4* __restrict__ packT,
    float* __restrict__ blocksum)
{
    __shared__ float pmin[4][64];   // per-wave mins for its 64 queries
    __shared__ float wsum[2];

    int tid  = threadIdx.x;
    int lane = tid & 63;
    int wave = tid >> 6;            // 0..3
    int qhalf = wave & 1;           // query half (64 queries)
    int chalf = wave >> 1;          // candidate half (2048 candidates)
    int l31  = lane & 31;
    bool lo  = lane < 32;

    int id = blockIdx.x;
    int ng = id & 31; id >>= 5;     // query group (128 queries)
    int b  = id & 15; id >>= 4;
    int dir = id;                   // 0: queries=pred, candidates=target

    const float4* qpack = dir ? packT : packP;
    const float4* cpack = dir ? packP : packT;

    // Two B fragments per wave: queries [qbase, qbase+32) and [qbase+32, qbase+64).
    size_t qbase = (size_t)b * NPTS + ng * 128 + qhalf * 64;
    Pack16 prA, prB;
    prA.f4 = qpack[qbase + l31];
    prB.f4 = qpack[qbase + 32 + l31];
    half8 bfragA = make_bfrag(prA, lo);
    half8 bfragB = make_bfrag(prB, lo);

    const float4* cb = cpack + (size_t)b * NPTS + chalf * 2048;

    floatx16 zero, mnA, mnB;
#pragma unroll
    for (int r = 0; r < 16; ++r) { zero[r] = 0.0f; mnA[r] = 1e30f; mnB[r] = 1e30f; }

    // 32 tiles x 64 candidates. Each load-pair feeds TWO independent MFMA/min
    // chains (bfragA vs bfragB) -> MFMA result latency on one chain overlaps
    // VALU issue on the other. (The R9 structure — the proven ILP winner.)
#pragma unroll 2
    for (int t = 0; t < 32; ++t) {
        Pack16 a0, a1;
        a0.f4 = cb[t * 64 + l31];                 // half-wave broadcast, L1/L2-served
        a1.f4 = cb[t * 64 + 32 + l31];
        floatx16 d0 = __builtin_amdgcn_mfma_f32_32x32x16_f16(a0.h8, bfragA, zero, 0, 0, 0);
        floatx16 d1 = __builtin_amdgcn_mfma_f32_32x32x16_f16(a0.h8, bfragB, zero, 0, 0, 0);
#pragma unroll
        for (int r = 0; r < 16; ++r) mnA[r] = fminf(d0[r], mnA[r]);
#pragma unroll
        for (int r = 0; r < 16; ++r) mnB[r] = fminf(d1[r], mnB[r]);
        floatx16 d2 = __builtin_amdgcn_mfma_f32_32x32x16_f16(a1.h8, bfragA, zero, 0, 0, 0);
        floatx16 d3 = __builtin_amdgcn_mfma_f32_32x32x16_f16(a1.h8, bfragB, zero, 0, 0, 0);
#pragma unroll
        for (int r = 0; r < 16; ++r) mnA[r] = fminf(d2[r], mnA[r]);
#pragma unroll
        for (int r = 0; r < 16; ++r) mnB[r] = fminf(d3[r], mnB[r]);
    }

    // Per-lane 16-reg min trees, fold row-halves across lane^32, publish both
    // query sets (cols l31 / l31+32 of pmin row).
    float mA = fminf(fminf(fminf(mnA[0], mnA[1]),   fminf(mnA[2], mnA[3])),
                     fminf(fminf(mnA[4], mnA[5]),   fminf(mnA[6], mnA[7])));
    mA = fminf(mA, fminf(fminf(fminf(mnA[8], mnA[9]),   fminf(mnA[10], mnA[11])),
                         fminf(fminf(mnA[12], mnA[13]), fminf(mnA[14], mnA[15]))));
    float mB = fminf(fminf(fminf(mnB[0], mnB[1]),   fminf(mnB[2], mnB[3])),
                     fminf(fminf(mnB[4], mnB[5]),   fminf(mnB[6], mnB[7])));
    mB = fminf(mB, fminf(fminf(fminf(mnB[8], mnB[9]),   fminf(mnB[10], mnB[11])),
                         fminf(fminf(mnB[12], mnB[13]), fminf(mnB[14], mnB[15]))));
    mA = fminf(mA, __shfl_xor(mA, 32));
    mB = fminf(mB, __shfl_xor(mB, 32));
    if (lo) {
        pmin[wave][l31]      = mA;
        pmin[wave][l31 + 32] = mB;
    }
    __syncthreads();

    // Waves 0-1: all 64 lanes finish one query each (query = ng*128 + wave*64 + lane):
    // merge candidate halves, add |p|^2, sqrt, full-wave sum.
    if (wave < 2) {
        float mm = fminf(pmin[wave][lane], pmin[wave + 2][lane]);
        Pack16 pr;
        pr.f4 = qpack[(size_t)b * NPTS + ng * 128 + wave * 64 + lane];
        float psq = (float)pr.h[3] + (float)pr.h[4];
        float dist = sqrtf(fmaxf(mm + psq, 0.0f));
#pragma unroll
        for (int off = 1; off <= 32; off <<= 1)
            dist += __shfl_xor(dist, off);
        if (lane == 0) wsum[wave] = dist;
    }
    __syncthreads();

    if (tid == 0)
        blocksum[blockIdx.x] = wsum[0] + wsum[1];
}

__global__ __launch_bounds__(256) void chamfer_finish(
    const float4* __restrict__ bs, float* __restrict__ out)
{
    __shared__ float ws[4];
    int tid = threadIdx.x;
    float4 v = bs[tid];                   // 1024 block sums = 256 thr x float4
    float s = (v.x + v.y) + (v.z + v.w);
#pragma unroll
    for (int off = 1; off <= 32; off <<= 1)
        s += __shfl_xor(s, off);
    int lane = tid & 63, wave = tid >> 6;
    if (lane == 0) ws[wave] = s;
    __syncthreads();
    if (tid == 0) out[0] = (ws[0] + ws[1] + ws[2] + ws[3]) * (1.0f / (float)NITEMS);
}

extern "C" void kernel_launch(void* const* d_in, const int* in_sizes, int n_in,
                              void* d_out, int out_size, void* d_ws, size_t ws_size,
                              hipStream_t stream) {
    const float* pred   = (const float*)d_in[0];
    const float* target = (const float*)d_in[1];
    float* out = (float*)d_out;

    float4* packP = (float4*)d_ws;                              // 1 MB
    float4* packT = packP + (size_t)BATCH * NPTS;               // 1 MB
    float*  blocksum = (float*)(packT + (size_t)BATCH * NPTS);  // 4 KB

    chamfer_prep<<<NITEMS / 256, 256, 0, stream>>>(pred, target, packP, packT);
    chamfer_main<<<MAIN_BLOCKS, THREADS, 0, stream>>>(packP, packT, blocksum);
    chamfer_finish<<<1, 256, 0, stream>>>((const float4*)blocksum, out);
}

// Round 13
// 76.064 us; speedup vs baseline: 1.0522x; 1.0005x over previous
//
#include <hip/hip_runtime.h>
#include <math.h>
#include <stdint.h>

// Chamfer loss, B=16, N=M=4096, D=3, fp32 in/out — MFMA formulation, R13.
// == R12/R9 structure + software-pipelined MFMA-result consumption ==
//
// d^2(p,t) = |p|^2 + (|t|^2 - 2 p.t); the bracket via v_mfma_f32_32x32x16_f16:
//   A row (candidate): [tx, ty, tz, h1, h2, 0,0,0]   (k=0..7; hi-lane k=8..15 garbage)
//   B col (query):     [-2px,-2py,-2pz, 1, 1, 0,0,0] (k=0..7; k=8..15 ZERO -> annihilates A garbage)
// h1+h2 = two-f16 split of |t|^2 (fp32-accurate). f16 products are exact in the
// fp32 accumulator; only error is f16 point quantization (~1e-3 absmax, passes).
//
// Session ledger: R9/R12 = 75.9/76.1 us (best). Neutral: TLP (R8), min-VALU
// count (R10). Won: chain ILP (R9, -5us). Lost: atomics+fence epilogue
// (R4-R6), LDS staging via global_load_lds (R4), prep fusion (R11).
// R13 theory: the residual main stall is the same-wave MFMA-result read
// hazard — in R12 only ONE 8-cyc MFMA separates d0's issue from the VALU
// read of its 16-reg result (~16-20 cyc write latency), and R8 proved other
// waves don't fill those wait states. Fix: consume tile t-1's results while
// issuing tile t's MFMAs (1-tile rotate) -> >=2 MFMA issues + 32 VALU insts
// between every MFMA and its first read. Liveness ~150 VGPR ->
// launch_bounds(256,3) (occupancy-insensitive per R8) to avoid spill.
//
// Fixed cost context: harness re-poisons ~256 MB ws each timed iter = ~41.4 us
// of fillBuffer at 81% HBM peak inside dur_us + ~8 us launch overhead.

#define BATCH   16
#define NPTS    4096
#define THREADS 256                            // 4 waves/block
#define NITEMS  (2 * BATCH * NPTS)             // 131072
#define MAIN_BLOCKS (2 * BATCH * (NPTS / 128)) // 1024: 128 queries per block

typedef __attribute__((ext_vector_type(8)))  _Float16 half8;
typedef __attribute__((ext_vector_type(16))) float    floatx16;

union Pack16 { float4 f4; _Float16 h[8]; half8 h8; };

__global__ __launch_bounds__(256) void chamfer_prep(
    const float* __restrict__ pred, const float* __restrict__ target,
    float4* __restrict__ packP, float4* __restrict__ packT)
{
    int g = blockIdx.x * 256 + threadIdx.x;       // 0..131071
    int arr = g >> 16;                            // 0=pred, 1=target
    int pt  = g & 65535;                          // b*NPTS + n
    const float* src = arr ? target : pred;
    float x = src[pt * 3 + 0];
    float y = src[pt * 3 + 1];
    float z = src[pt * 3 + 2];
    _Float16 hx = (_Float16)x, hy = (_Float16)y, hz = (_Float16)z;
    float xf = (float)hx, yf = (float)hy, zf = (float)hz;
    float t = xf * xf + yf * yf + zf * zf;        // |q|^2 of the QUANTIZED point
    _Float16 h1 = (_Float16)t;
    _Float16 h2 = (_Float16)(t - (float)h1);
    Pack16 p;
    p.h[0] = hx; p.h[1] = hy; p.h[2] = hz; p.h[3] = h1; p.h[4] = h2;
    p.h[5] = (_Float16)0.0f; p.h[6] = (_Float16)0.0f; p.h[7] = (_Float16)0.0f;
    (arr ? packT : packP)[pt] = p.f4;
}

__device__ inline half8 make_bfrag(const Pack16& praw, bool lo) {
    half8 f;
#pragma unroll
    for (int i = 0; i < 8; ++i) f[i] = (_Float16)0.0f;
    if (lo) {
        f[0] = (_Float16)(praw.h[0] * (_Float16)-2.0f);  // exact x2 scale
        f[1] = (_Float16)(praw.h[1] * (_Float16)-2.0f);
        f[2] = (_Float16)(praw.h[2] * (_Float16)-2.0f);
        f[3] = (_Float16)1.0f;
        f[4] = (_Float16)1.0f;
    }
    return f;
}

__global__ __launch_bounds__(THREADS, 3) void chamfer_main(
    const float4* __restrict__ packP, const float4* __restrict__ packT,
    float* __restrict__ blocksum)
{
    __shared__ float pmin[4][64];   // per-wave mins for its 64 queries
    __shared__ float wsum[2];

    int tid  = threadIdx.x;
    int lane = tid & 63;
    int wave = tid >> 6;            // 0..3
    int qhalf = wave & 1;           // query half (64 queries)
    int chalf = wave >> 1;          // candidate half (2048 candidates)
    int l31  = lane & 31;
    bool lo  = lane < 32;

    int id = blockIdx.x;
    int ng = id & 31; id >>= 5;     // query group (128 queries)
    int b  = id & 15; id >>= 4;
    int dir = id;                   // 0: queries=pred, candidates=target

    const float4* qpack = dir ? packT : packP;
    const float4* cpack = dir ? packP : packT;

    // Two B fragments per wave: queries [qbase, qbase+32) and [qbase+32, qbase+64).
    size_t qbase = (size_t)b * NPTS + ng * 128 + qhalf * 64;
    Pack16 prA, prB;
    prA.f4 = qpack[qbase + l31];
    prB.f4 = qpack[qbase + 32 + l31];
    half8 bfragA = make_bfrag(prA, lo);
    half8 bfragB = make_bfrag(prB, lo);

    const float4* cb = cpack + (size_t)b * NPTS + chalf * 2048;

    floatx16 mnA, mnB;
#pragma unroll
    for (int r = 0; r < 16; ++r) { mnA[r] = 1e30f; mnB[r] = 1e30f; }
    floatx16 zero;
#pragma unroll
    for (int r = 0; r < 16; ++r) zero[r] = 0.0f;

    // Software-pipelined: issue tile t's 4 MFMAs while min-consuming tile
    // t-1's results. Every MFMA gets >=2 MFMA issues + 32 VALU insts between
    // its issue and the first VALU read of its result regs.
    floatx16 d0p, d1p, d2p, d3p;
    {
        Pack16 a0, a1;
        a0.f4 = cb[l31];
        a1.f4 = cb[32 + l31];
        d0p = __builtin_amdgcn_mfma_f32_32x32x16_f16(a0.h8, bfragA, zero, 0, 0, 0);
        d1p = __builtin_amdgcn_mfma_f32_32x32x16_f16(a0.h8, bfragB, zero, 0, 0, 0);
        d2p = __builtin_amdgcn_mfma_f32_32x32x16_f16(a1.h8, bfragA, zero, 0, 0, 0);
        d3p = __builtin_amdgcn_mfma_f32_32x32x16_f16(a1.h8, bfragB, zero, 0, 0, 0);
    }
#pragma unroll 2
    for (int t = 1; t < 32; ++t) {
        Pack16 a0, a1;
        a0.f4 = cb[t * 64 + l31];                 // half-wave broadcast, L1/L2-served
        a1.f4 = cb[t * 64 + 32 + l31];
        floatx16 e0 = __builtin_amdgcn_mfma_f32_32x32x16_f16(a0.h8, bfragA, zero, 0, 0, 0);
        floatx16 e1 = __builtin_amdgcn_mfma_f32_32x32x16_f16(a0.h8, bfragB, zero, 0, 0, 0);
        // consume previous tile's A-chain while e0/e1 cook
#pragma unroll
        for (int r = 0; r < 16; ++r) mnA[r] = fminf(fminf(d0p[r], d2p[r]), mnA[r]);
        floatx16 e2 = __builtin_amdgcn_mfma_f32_32x32x16_f16(a1.h8, bfragA, zero, 0, 0, 0);
        // previous tile's B-chain
#pragma unroll
        for (int r = 0; r < 16; ++r) mnB[r] = fminf(fminf(d1p[r], d3p[r]), mnB[r]);
        floatx16 e3 = __builtin_amdgcn_mfma_f32_32x32x16_f16(a1.h8, bfragB, zero, 0, 0, 0);
        d0p = e0; d1p = e1; d2p = e2; d3p = e3;   // register rotate (SSA rename)
    }
    // drain the last tile
#pragma unroll
    for (int r = 0; r < 16; ++r) mnA[r] = fminf(fminf(d0p[r], d2p[r]), mnA[r]);
#pragma unroll
    for (int r = 0; r < 16; ++r) mnB[r] = fminf(fminf(d1p[r], d3p[r]), mnB[r]);

    // Per-lane 16-reg min trees, fold row-halves across lane^32, publish both
    // query sets (cols l31 / l31+32 of pmin row).
    float mA = fminf(fminf(fminf(mnA[0], mnA[1]),   fminf(mnA[2], mnA[3])),
                     fminf(fminf(mnA[4], mnA[5]),   fminf(mnA[6], mnA[7])));
    mA = fminf(mA, fminf(fminf(fminf(mnA[8], mnA[9]),   fminf(mnA[10], mnA[11])),
                         fminf(fminf(mnA[12], mnA[13]), fminf(mnA[14], mnA[15]))));
    float mB = fminf(fminf(fminf(mnB[0], mnB[1]),   fminf(mnB[2], mnB[3])),
                     fminf(fminf(mnB[4], mnB[5]),   fminf(mnB[6], mnB[7])));
    mB = fminf(mB, fminf(fminf(fminf(mnB[8], mnB[9]),   fminf(mnB[10], mnB[11])),
                         fminf(fminf(mnB[12], mnB[13]), fminf(mnB[14], mnB[15]))));
    mA = fminf(mA, __shfl_xor(mA, 32));
    mB = fminf(mB, __shfl_xor(mB, 32));
    if (lo) {
        pmin[wave][l31]      = mA;
        pmin[wave][l31 + 32] = mB;
    }
    __syncthreads();

    // Waves 0-1: all 64 lanes finish one query each (query = ng*128 + wave*64 + lane):
    // merge candidate halves, add |p|^2, sqrt, full-wave sum.
    if (wave < 2) {
        float mm = fminf(pmin[wave][lane], pmin[wave + 2][lane]);
        Pack16 pr;
        pr.f4 = qpack[(size_t)b * NPTS + ng * 128 + wave * 64 + lane];
        float psq = (float)pr.h[3] + (float)pr.h[4];
        float dist = sqrtf(fmaxf(mm + psq, 0.0f));
#pragma unroll
        for (int off = 1; off <= 32; off <<= 1)
            dist += __shfl_xor(dist, off);
        if (lane == 0) wsum[wave] = dist;
    }
    __syncthreads();

    if (tid == 0)
        blocksum[blockIdx.x] = wsum[0] + wsum[1];
}

__global__ __launch_bounds__(256) void chamfer_finish(
    const float4* __restrict__ bs, float* __restrict__ out)
{
    __shared__ float ws[4];
    int tid = threadIdx.x;
    float4 v = bs[tid];                   // 1024 block sums = 256 thr x float4
    float s = (v.x + v.y) + (v.z + v.w);
#pragma unroll
    for (int off = 1; off <= 32; off <<= 1)
        s += __shfl_xor(s, off);
    int lane = tid & 63, wave = tid >> 6;
    if (lane == 0) ws[wave] = s;
    __syncthreads();
    if (tid == 0) out[0] = (ws[0] + ws[1] + ws[2] + ws[3]) * (1.0f / (float)NITEMS);
}

extern "C" void kernel_launch(void* const* d_in, const int* in_sizes, int n_in,
                              void* d_out, int out_size, void* d_ws, size_t ws_size,
                              hipStream_t stream) {
    const float* pred   = (const float*)d_in[0];
    const float* target = (const float*)d_in[1];
    float* out = (float*)d_out;

    float4* packP = (float4*)d_ws;                              // 1 MB
    float4* packT = packP + (size_t)BATCH * NPTS;               // 1 MB
    float*  blocksum = (float*)(packT + (size_t)BATCH * NPTS);  // 4 KB

    chamfer_prep<<<NITEMS / 256, 256, 0, stream>>>(pred, target, packP, packT);
    chamfer_main<<<MAIN_BLOCKS, THREADS, 0, stream>>>(packP, packT, blocksum);
    chamfer_finish<<<1, 256, 0, stream>>>((const float4*)blocksum, out);
}